// Round 12
// baseline (392.157 us; speedup 1.0000x reference)
//
#include <hip/hip_runtime.h>

typedef __attribute__((ext_vector_type(8))) __bf16 bf16x8;
typedef __attribute__((ext_vector_type(4))) float f32x4;
typedef __attribute__((ext_vector_type(8))) unsigned short u16x8;

#define B_ROWS 131072
#define EDIM   256
#define N_E    1024
#define BMR    64          // rows per search block (16 per wave)
#define CHUNKS 32          // 32 chunks x 32 codes (2 halves of 16)
#define CAP    16
#define OROWS  32          // rows per output block

#define OUT1 ((size_t)B_ROWS * EDIM)       // loss scalar
#define OUT2 (OUT1 + 1)                    // indices [B]
#define OUT3 (OUT2 + B_ROWS)               // perplexity scalar

// ws layout
#define WS_EMBT  0          // emb16T: [32 granules][1024 codes][8 bf16] = 524288 B
#define WS_ESQ   524288     // 1024 float
#define WS_COUNT 528384     // 1024 uint
#define WS_LOSS  532480     // 1 double

__device__ __forceinline__ unsigned short f2bf(float f) {   // RN to bf16
    unsigned u = __float_as_uint(f);
    return (unsigned short)((u + 0x7FFFu + ((u >> 16) & 1u)) >> 16);
}
__device__ __forceinline__ unsigned encf(float f) {          // order-preserving
    unsigned u = __float_as_uint(f);
    return u ^ (unsigned)(((int)u >> 31) | 0x80000000);
}
__device__ __forceinline__ float decf(unsigned x) {
    return (x & 0x80000000u) ? __uint_as_float(x ^ 0x80000000u)
                             : __uint_as_float(~x);
}
__device__ __forceinline__ float med3f(float a, float b, float c) {
#if __has_builtin(__builtin_amdgcn_fmed3f)
    return __builtin_amdgcn_fmed3f(a, b, c);
#else
    return fmaxf(fminf(a, b), fminf(fmaxf(a, b), c));
#endif
}

// numpy pairwise sum-of-squares over 128 elems (exact tree, no contraction)
__device__ inline float pw128_sq(const float* p) {
    float4 v0 = *(const float4*)p, v1 = *(const float4*)(p + 4);
    float r[8];
    r[0] = __fmul_rn(v0.x, v0.x); r[1] = __fmul_rn(v0.y, v0.y);
    r[2] = __fmul_rn(v0.z, v0.z); r[3] = __fmul_rn(v0.w, v0.w);
    r[4] = __fmul_rn(v1.x, v1.x); r[5] = __fmul_rn(v1.y, v1.y);
    r[6] = __fmul_rn(v1.z, v1.z); r[7] = __fmul_rn(v1.w, v1.w);
    for (int i = 8; i < 128; i += 8) {
        v0 = *(const float4*)(p + i); v1 = *(const float4*)(p + i + 4);
        r[0] = __fadd_rn(r[0], __fmul_rn(v0.x, v0.x));
        r[1] = __fadd_rn(r[1], __fmul_rn(v0.y, v0.y));
        r[2] = __fadd_rn(r[2], __fmul_rn(v0.z, v0.z));
        r[3] = __fadd_rn(r[3], __fmul_rn(v0.w, v0.w));
        r[4] = __fadd_rn(r[4], __fmul_rn(v1.x, v1.x));
        r[5] = __fadd_rn(r[5], __fmul_rn(v1.y, v1.y));
        r[6] = __fadd_rn(r[6], __fmul_rn(v1.z, v1.z));
        r[7] = __fadd_rn(r[7], __fmul_rn(v1.w, v1.w));
    }
    float s01 = __fadd_rn(r[0], r[1]), s23 = __fadd_rn(r[2], r[3]);
    float s45 = __fadd_rn(r[4], r[5]), s67 = __fadd_rn(r[6], r[7]);
    return __fadd_rn(__fadd_rn(s01, s23), __fadd_rn(s45, s67));
}

// exact fp32 distance, bit-identical to the verified rounds-1..11 chain
__device__ inline float exact_d(const float* zp, const float* ep, float zsq, float eq) {
    const float4* z4 = (const float4*)zp;
    const float4* e4 = (const float4*)ep;
    float acc = 0.f;
#pragma unroll 8
    for (int k = 0; k < 64; ++k) {
        float4 a = z4[k], b = e4[k];
        acc = __fmaf_rn(a.x, b.x, acc);
        acc = __fmaf_rn(a.y, b.y, acc);
        acc = __fmaf_rn(a.z, b.z, acc);
        acc = __fmaf_rn(a.w, b.w, acc);
    }
    return __fsub_rn(__fadd_rn(zsq, eq), 2.0f * acc);
}

// emb fp32 -> bf16, TRANSPOSED layout: embT[g][n] = 16B granule g of code n
__global__ void prep_emb(const float* __restrict__ emb,
                         unsigned short* __restrict__ embT,
                         float* __restrict__ esqg)
{
    int n = blockIdx.x, t = threadIdx.x;          // 1024 blocks x 64 threads
    const float4 v = ((const float4*)(emb + (size_t)n * EDIM))[t];
    ushort4 o = { f2bf(v.x), f2bf(v.y), f2bf(v.z), f2bf(v.w) };
    int g = t >> 1, j0 = (t & 1) * 4;
    *(ushort4*)(embT + ((size_t)g * N_E + n) * 8 + j0) = o;
    if (t < 2) {
        float h = pw128_sq(emb + (size_t)n * EDIM + 128 * t);
        float ho = __shfl_xor(h, 1);
        if (t == 0) esqg[n] = __fadd_rn(h, ho);
    }
}

// top-3 sorted insert (codes arrive in ascending order; strict < = first-index ties)
#define INS(s_, code_, r_)                                                  \
    {                                                                       \
        bool lt1 = (s_) < bd1[r_];                                          \
        bool lt2 = (s_) < bd2[r_];                                          \
        bd3[r_] = med3f((s_), bd2[r_], bd3[r_]);                            \
        bd2[r_] = med3f((s_), bd1[r_], bd2[r_]);                            \
        bd1[r_] = fminf((s_), bd1[r_]);                                     \
        int low_ = cp_[r_] & 0xFFFF;                                        \
        cp_[r_] = lt1 ? ((code_) | (low_ << 16))                            \
                      : (lt2 ? (low_ | ((code_) << 16)) : cp_[r_]);         \
    }

__global__ __launch_bounds__(256, 4) void vq_search(
    const float* __restrict__ z, const float* __restrict__ emb,
    const unsigned short* __restrict__ embT, const float* __restrict__ esqg,
    float* __restrict__ out, unsigned int* __restrict__ count)
{
    __shared__ float esq_s[N_E];                     // 4 KB
    __shared__ float zsq_s[BMR], S_s[BMR];
    __shared__ unsigned cnt[BMR];
    __shared__ unsigned short list[BMR][CAP];        // 2 KB
    __shared__ int rowbest[BMR];
    __shared__ unsigned long long fb4[4];

    const int tid  = threadIdx.x;
    const int blk  = blockIdx.x;
    const int lane = tid & 63;
    const int w    = tid >> 6;
    const int col  = lane & 15;
    const int quad = lane >> 4;
    const int row0 = w * 16;       // this wave owns rows row0..row0+15, ALL codes

    const float* zb = z + (size_t)blk * BMR * EDIM;

    for (int i = tid; i < N_E; i += 256) esq_s[i] = esqg[i];
    if (tid < BMR) cnt[tid] = 0u;

    // ---- A fragments from global z (one-time): 16 rows/wave = 32 VGPR ----
    bf16x8 afr[8];
    {
        int row = row0 + col;
#pragma unroll
        for (int ks = 0; ks < 8; ++ks) {
            const float* p = zb + row * EDIM + ((ks * 4 + quad) << 3);
            float4 a0 = *(const float4*)p;
            float4 a1 = *(const float4*)(p + 4);
            u16x8 t = { f2bf(a0.x), f2bf(a0.y), f2bf(a0.z), f2bf(a0.w),
                        f2bf(a1.x), f2bf(a1.y), f2bf(a1.z), f2bf(a1.w) };
            afr[ks] = *(bf16x8*)&t;
        }
    }

    // ---- exact zsq (np-pairwise) + S = sum|z| (bound only) ----
    if (tid < 128) {
        int row = tid >> 1, half = tid & 1;
        const float* p = zb + row * EDIM + half * 128;
        float h = pw128_sq(p);
        const float4* p4 = (const float4*)p;
        float4 sv = {0.f, 0.f, 0.f, 0.f};
#pragma unroll
        for (int jj = 0; jj < 32; ++jj) {
            float4 vv = p4[jj];
            sv.x += fabsf(vv.x); sv.y += fabsf(vv.y);
            sv.z += fabsf(vv.z); sv.w += fabsf(vv.w);
        }
        float sa = (sv.x + sv.y) + (sv.z + sv.w);
        float ho = __shfl_xor(h, 1);
        float so = __shfl_xor(sa, 1);
        if (half == 0) {
            zsq_s[row] = __fadd_rn(h, ho);
            S_s[row]   = (sa + so) * 1.001f;
        }
    }
    __syncthreads();

    // per-lane constant byte-offsets (in shorts) for B-granule loads, code half 0
    int koff[8];
#pragma unroll
    for (int ks = 0; ks < 8; ++ks)
        koff[ks] = ((((ks * 4 + quad) << 10) + col) << 3);

    // ================= barrier-free single-pass chunk loop =================
    // 4 slots (rows row0 + quad*4 + r); two scores inserted per chunk per slot
    float bd1[4], bd2[4], bd3[4];
    int   cp_[4];
#pragma unroll
    for (int r = 0; r < 4; ++r) {
        bd1[r] = INFINITY; bd2[r] = INFINITY; bd3[r] = INFINITY; cp_[r] = 0;
    }

    for (int c = 0; c < CHUNKS; ++c) {
        const unsigned short* cb = embT + (c << 8);      // + c*32 codes (uniform)
        // ---- half 0: codes c*32 + col ----
        {
            u16x8 bfr[8];
#pragma unroll
            for (int ks = 0; ks < 8; ++ks)
                bfr[ks] = *(const u16x8*)(cb + koff[ks]);
            f32x4 acc = {0.f, 0.f, 0.f, 0.f};
#pragma unroll
            for (int ks = 0; ks < 8; ++ks)
                acc = __builtin_amdgcn_mfma_f32_16x16x32_bf16(afr[ks], *(bf16x8*)&bfr[ks], acc, 0, 0, 0);
            const int codeN = (c << 5) + col;
            const float eqv = esq_s[codeN];
#pragma unroll
            for (int r = 0; r < 4; ++r) {
                float s = __fmaf_rn(-2.0f, acc[r], eqv);
                INS(s, codeN, r);
            }
        }
        // ---- half 1: codes c*32 + 16 + col ----
        {
            u16x8 bfr[8];
#pragma unroll
            for (int ks = 0; ks < 8; ++ks)
                bfr[ks] = *(const u16x8*)(cb + koff[ks] + 128);
            f32x4 acc = {0.f, 0.f, 0.f, 0.f};
#pragma unroll
            for (int ks = 0; ks < 8; ++ks)
                acc = __builtin_amdgcn_mfma_f32_16x16x32_bf16(afr[ks], *(bf16x8*)&bfr[ks], acc, 0, 0, 0);
            const int codeN = (c << 5) + 16 + col;
            const float eqv = esq_s[codeN];
#pragma unroll
            for (int r = 0; r < 4; ++r) {
                float s = __fmaf_rn(-2.0f, acc[r], eqv);
                INS(s, codeN, r);
            }
        }
    }

    // ---- butterfly allreduce of bd1 across 16 code-columns (lex min) ----
    // every lane ends with the global row-min -> wave-local threshold, no LDS
    float th[4];
#pragma unroll
    for (int r = 0; r < 4; ++r) {
        unsigned long long kk =
            ((unsigned long long)encf(bd1[r]) << 32) | (unsigned)(cp_[r] & 0xFFFF);
#pragma unroll
        for (int msk = 1; msk <= 8; msk <<= 1) {
            unsigned long long o = __shfl_xor(kk, msk);
            if (o < kk) kk = o;
        }
        int row = row0 + quad * 4 + r;
        th[r] = decf((unsigned)(kk >> 32)) + (S_s[row] * (1.0f / 131072.0f) + 1e-4f);
    }

    // ---- candidate push + overflow flag (top-3 soundness) ----
#pragma unroll
    for (int r = 0; r < 4; ++r) {
        int row = row0 + quad * 4 + r;
        if (__builtin_expect(bd1[r] <= th[r], 0)) {
            unsigned i = atomicAdd(&cnt[row], 1u);
            if (i < CAP) list[row][i] = (unsigned short)(cp_[r] & 0xFFFF);
        }
        if (__builtin_expect(bd2[r] <= th[r], 0)) {
            unsigned i = atomicAdd(&cnt[row], 1u);
            if (i < CAP) list[row][i] = (unsigned short)((unsigned)cp_[r] >> 16);
        }
        if (__builtin_expect(bd3[r] <= th[r], 0))
            atomicAdd(&cnt[row], 1000u);     // may have dropped a candidate
    }
    __syncthreads();

    // ---- exact rescore of candidates (4 lanes / row, z from L2) ----
    {
        int row = tid >> 2, j = tid & 3;
        int cn = (int)cnt[row];
        unsigned long long bkey = ~0ull;
        float zq = zsq_s[row];
        const float* zrow = zb + row * EDIM;
        if (cn <= CAP) {
            for (int i = j; i < cn; i += 4) {
                int n = (int)list[row][i];
                float d = exact_d(zrow, emb + (size_t)n * EDIM, zq, esq_s[n]);
                unsigned long long k2 = ((unsigned long long)encf(d) << 32) | (unsigned)n;
                if (k2 < bkey) bkey = k2;
            }
        }
#pragma unroll
        for (int m = 1; m <= 2; m <<= 1) {
            unsigned long long o = __shfl_xor(bkey, m);
            if (o < bkey) bkey = o;
        }
        if (j == 0) rowbest[row] = (cn <= CAP) ? (int)(bkey & 0xFFFFFFFFu) : -1;
    }
    __syncthreads();

    // ---- overflow rows: full exact scan, block-cooperative (rare) ----
    for (int r = 0; r < BMR; ++r) {
        if (rowbest[r] != -1) continue;       // uniform branch
        const float* zr = zb + r * EDIM;
        float zqr = zsq_s[r];
        unsigned long long k = ~0ull;
        for (int ci = 0; ci < 4; ++ci) {
            int n = tid + ci * 256;
            float d = exact_d(zr, emb + (size_t)n * EDIM, zqr, esq_s[n]);
            unsigned long long k2 = ((unsigned long long)encf(d) << 32) | (unsigned)n;
            if (k2 < k) k = k2;
        }
#pragma unroll
        for (int msk = 1; msk <= 32; msk <<= 1) {
            unsigned long long o = __shfl_xor(k, msk);
            if (o < k) k = o;
        }
        if (lane == 0) fb4[w] = k;
        __syncthreads();
        if (tid == 0) {
            unsigned long long m0 = fb4[0] < fb4[1] ? fb4[0] : fb4[1];
            unsigned long long m1 = fb4[2] < fb4[3] ? fb4[2] : fb4[3];
            rowbest[r] = (int)((m0 < m1 ? m0 : m1) & 0xFFFFFFFFu);
        }
        __syncthreads();
    }

    // ---- write indices + histogram (output kernel does the heavy lifting) ----
    if (tid < BMR) {
        int bn = rowbest[tid];
        out[OUT2 + (size_t)blk * BMR + tid] = (float)bn;
        atomicAdd(&count[bn], 1u);
    }
}

// pure streaming: gather z_q = emb[idx], STE output, loss partial
__global__ void vq_output(const float* __restrict__ z, const float* __restrict__ emb,
                          float* __restrict__ out, double* __restrict__ lossSum)
{
    __shared__ double red4s[4];
    const int tid = threadIdx.x;
    const int blk = blockIdx.x;
    const int lane = tid & 63;
    const int w   = tid >> 6;
    const int row = tid >> 3;      // 0..31
    const int q   = tid & 7;       // 8 threads per row
    const size_t grow = (size_t)blk * OROWS + row;
    const int bn = (int)out[OUT2 + grow];
    const float4* zp4 = (const float4*)(z + grow * EDIM);
    const float4* ebr = (const float4*)(emb + (size_t)bn * EDIM);
    float4* outr = (float4*)(out + grow * EDIM);
    double lacc = 0.0;
#pragma unroll
    for (int i = 0; i < 8; ++i) {
        int k4 = q + i * 8;
        float4 zv = zp4[k4];
        float4 ev = ebr[k4];
        float4 o; float sd;
        sd = __fsub_rn(ev.x, zv.x); o.x = __fadd_rn(zv.x, sd); lacc += (double)__fmul_rn(sd, sd);
        sd = __fsub_rn(ev.y, zv.y); o.y = __fadd_rn(zv.y, sd); lacc += (double)__fmul_rn(sd, sd);
        sd = __fsub_rn(ev.z, zv.z); o.z = __fadd_rn(zv.z, sd); lacc += (double)__fmul_rn(sd, sd);
        sd = __fsub_rn(ev.w, zv.w); o.w = __fadd_rn(zv.w, sd); lacc += (double)__fmul_rn(sd, sd);
        outr[k4] = o;
    }
#pragma unroll
    for (int msk = 1; msk <= 32; msk <<= 1) lacc += __shfl_xor(lacc, msk);
    if (lane == 0) red4s[w] = lacc;
    __syncthreads();
    if (tid == 0) atomicAdd(lossSum, red4s[0] + red4s[1] + red4s[2] + red4s[3]);
}

__global__ void vq_finalize(const unsigned int* __restrict__ count,
                            const double* __restrict__ lossSum,
                            float* __restrict__ out)
{
    __shared__ double red[1024];
    int t = threadIdx.x;
    double em = (double)count[t] * (1.0 / 131072.0);
    red[t] = em * log(em + 1e-10);
    __syncthreads();
    for (int s = 512; s > 0; s >>= 1) {
        if (t < s) red[t] += red[t + s];
        __syncthreads();
    }
    if (t == 0) {
        out[OUT3] = (float)exp(-red[0]);
        double m = lossSum[0] * (1.0 / 33554432.0);
        out[OUT1] = (float)(1.25 * m);
    }
}

extern "C" void kernel_launch(void* const* d_in, const int* in_sizes, int n_in,
                              void* d_out, int out_size, void* d_ws, size_t ws_size,
                              hipStream_t stream) {
    const float* z   = (const float*)d_in[0];
    const float* emb = (const float*)d_in[1];
    float* out = (float*)d_out;

    unsigned short* embT = (unsigned short*)((char*)d_ws + WS_EMBT);
    float* esqg          = (float*)((char*)d_ws + WS_ESQ);
    unsigned int* count  = (unsigned int*)((char*)d_ws + WS_COUNT);
    double* lossSum      = (double*)((char*)d_ws + WS_LOSS);

    hipMemsetAsync((char*)d_ws + WS_COUNT, 0, 4104, stream);
    prep_emb<<<N_E, 64, 0, stream>>>(emb, embT, esqg);
    vq_search<<<B_ROWS / BMR, 256, 0, stream>>>(z, emb, embT, esqg, out, count);
    vq_output<<<B_ROWS / OROWS, 256, 0, stream>>>(z, emb, out, lossSum);
    vq_finalize<<<1, 1024, 0, stream>>>(count, lossSum, out);
}

// Round 13
// 391.061 us; speedup vs baseline: 1.0028x; 1.0028x over previous
//
#include <hip/hip_runtime.h>

typedef __attribute__((ext_vector_type(8))) __bf16 bf16x8;
typedef __attribute__((ext_vector_type(4))) float f32x4;
typedef __attribute__((ext_vector_type(8))) unsigned short u16x8;

#define B_ROWS 131072
#define EDIM   256
#define N_E    1024
#define BMR    64          // rows per scan block (16 per wave)
#define CHUNKS 32          // 32 chunks x 32 codes (2 halves of 16)
#define CAP    16
#define OROWS  32          // rows per output block

#define OUT1 ((size_t)B_ROWS * EDIM)       // loss scalar
#define OUT2 (OUT1 + 1)                    // indices [B]
#define OUT3 (OUT2 + B_ROWS)               // perplexity scalar
#define SCR_WORDS 10                       // per-row scratch record (u32s) in out[0..]

// ws layout
#define WS_EMBT  0          // emb16T: [32 granules][1024 codes][8 bf16] = 524288 B
#define WS_ESQ   524288     // 1024 float
#define WS_COUNT 528384     // 1024 uint
#define WS_LOSS  532480     // 1 double

__device__ __forceinline__ unsigned short f2bf(float f) {   // RN to bf16
    unsigned u = __float_as_uint(f);
    return (unsigned short)((u + 0x7FFFu + ((u >> 16) & 1u)) >> 16);
}
__device__ __forceinline__ unsigned encf(float f) {          // order-preserving
    unsigned u = __float_as_uint(f);
    return u ^ (unsigned)(((int)u >> 31) | 0x80000000);
}
__device__ __forceinline__ float decf(unsigned x) {
    return (x & 0x80000000u) ? __uint_as_float(x ^ 0x80000000u)
                             : __uint_as_float(~x);
}
__device__ __forceinline__ float med3f(float a, float b, float c) {
#if __has_builtin(__builtin_amdgcn_fmed3f)
    return __builtin_amdgcn_fmed3f(a, b, c);
#else
    return fmaxf(fminf(a, b), fminf(fmaxf(a, b), c));
#endif
}

// numpy pairwise sum-of-squares over 128 elems (exact tree, no contraction)
__device__ inline float pw128_sq(const float* p) {
    float4 v0 = *(const float4*)p, v1 = *(const float4*)(p + 4);
    float r[8];
    r[0] = __fmul_rn(v0.x, v0.x); r[1] = __fmul_rn(v0.y, v0.y);
    r[2] = __fmul_rn(v0.z, v0.z); r[3] = __fmul_rn(v0.w, v0.w);
    r[4] = __fmul_rn(v1.x, v1.x); r[5] = __fmul_rn(v1.y, v1.y);
    r[6] = __fmul_rn(v1.z, v1.z); r[7] = __fmul_rn(v1.w, v1.w);
    for (int i = 8; i < 128; i += 8) {
        v0 = *(const float4*)(p + i); v1 = *(const float4*)(p + i + 4);
        r[0] = __fadd_rn(r[0], __fmul_rn(v0.x, v0.x));
        r[1] = __fadd_rn(r[1], __fmul_rn(v0.y, v0.y));
        r[2] = __fadd_rn(r[2], __fmul_rn(v0.z, v0.z));
        r[3] = __fadd_rn(r[3], __fmul_rn(v0.w, v0.w));
        r[4] = __fadd_rn(r[4], __fmul_rn(v1.x, v1.x));
        r[5] = __fadd_rn(r[5], __fmul_rn(v1.y, v1.y));
        r[6] = __fadd_rn(r[6], __fmul_rn(v1.z, v1.z));
        r[7] = __fadd_rn(r[7], __fmul_rn(v1.w, v1.w));
    }
    float s01 = __fadd_rn(r[0], r[1]), s23 = __fadd_rn(r[2], r[3]);
    float s45 = __fadd_rn(r[4], r[5]), s67 = __fadd_rn(r[6], r[7]);
    return __fadd_rn(__fadd_rn(s01, s23), __fadd_rn(s45, s67));
}

// exact fp32 distance, bit-identical to the verified rounds-1..12 chain
__device__ inline float exact_d(const float* zp, const float* ep, float zsq, float eq) {
    const float4* z4 = (const float4*)zp;
    const float4* e4 = (const float4*)ep;
    float acc = 0.f;
#pragma unroll 8
    for (int k = 0; k < 64; ++k) {
        float4 a = z4[k], b = e4[k];
        acc = __fmaf_rn(a.x, b.x, acc);
        acc = __fmaf_rn(a.y, b.y, acc);
        acc = __fmaf_rn(a.z, b.z, acc);
        acc = __fmaf_rn(a.w, b.w, acc);
    }
    return __fsub_rn(__fadd_rn(zsq, eq), 2.0f * acc);
}

// emb fp32 -> bf16, TRANSPOSED layout: embT[g][n] = 16B granule g of code n
__global__ void prep_emb(const float* __restrict__ emb,
                         unsigned short* __restrict__ embT,
                         float* __restrict__ esqg)
{
    int n = blockIdx.x, t = threadIdx.x;          // 1024 blocks x 64 threads
    const float4 v = ((const float4*)(emb + (size_t)n * EDIM))[t];
    ushort4 o = { f2bf(v.x), f2bf(v.y), f2bf(v.z), f2bf(v.w) };
    int g = t >> 1, j0 = (t & 1) * 4;
    *(ushort4*)(embT + ((size_t)g * N_E + n) * 8 + j0) = o;
    if (t < 2) {
        float h = pw128_sq(emb + (size_t)n * EDIM + 128 * t);
        float ho = __shfl_xor(h, 1);
        if (t == 0) esqg[n] = __fadd_rn(h, ho);
    }
}

// top-3 sorted insert (codes arrive in ascending order; strict < = first-index ties)
#define INS(s_, code_, r_)                                                  \
    {                                                                       \
        bool lt1 = (s_) < bd1[r_];                                          \
        bool lt2 = (s_) < bd2[r_];                                          \
        bd3[r_] = med3f((s_), bd2[r_], bd3[r_]);                            \
        bd2[r_] = med3f((s_), bd1[r_], bd2[r_]);                            \
        bd1[r_] = fminf((s_), bd1[r_]);                                     \
        int low_ = cp_[r_] & 0xFFFF;                                        \
        cp_[r_] = lt1 ? ((code_) | (low_ << 16))                            \
                      : (lt2 ? (low_ | ((code_) << 16)) : cp_[r_]);         \
    }

// ============ S1: MFMA scan + threshold + candidate lists -> scratch ========
__global__ __launch_bounds__(256, 4) void vq_scan(
    const float* __restrict__ z, const unsigned short* __restrict__ embT,
    const float* __restrict__ esqg, float* __restrict__ out)
{
    __shared__ float esq_s[N_E];                     // 4 KB
    __shared__ float S_s[BMR];
    __shared__ unsigned cnt[BMR];
    __shared__ unsigned short list[BMR][CAP];        // 2 KB

    const int tid  = threadIdx.x;
    const int blk  = blockIdx.x;
    const int lane = tid & 63;
    const int w    = tid >> 6;
    const int col  = lane & 15;
    const int quad = lane >> 4;
    const int row0 = w * 16;       // this wave owns rows row0..row0+15, ALL codes

    const float* zb = z + (size_t)blk * BMR * EDIM;

    for (int i = tid; i < N_E; i += 256) esq_s[i] = esqg[i];
    if (tid < BMR) cnt[tid] = 0u;

    // ---- A fragments from global z (one-time): 16 rows/wave = 32 VGPR ----
    bf16x8 afr[8];
    {
        int row = row0 + col;
#pragma unroll
        for (int ks = 0; ks < 8; ++ks) {
            const float* p = zb + row * EDIM + ((ks * 4 + quad) << 3);
            float4 a0 = *(const float4*)p;
            float4 a1 = *(const float4*)(p + 4);
            u16x8 t = { f2bf(a0.x), f2bf(a0.y), f2bf(a0.z), f2bf(a0.w),
                        f2bf(a1.x), f2bf(a1.y), f2bf(a1.z), f2bf(a1.w) };
            afr[ks] = *(bf16x8*)&t;
        }
    }

    // ---- S = sum|z| per row (margin bound only) ----
    if (tid < 128) {
        int row = tid >> 1, half = tid & 1;
        const float4* p4 = (const float4*)(zb + row * EDIM + half * 128);
        float4 sv = {0.f, 0.f, 0.f, 0.f};
#pragma unroll
        for (int jj = 0; jj < 32; ++jj) {
            float4 vv = p4[jj];
            sv.x += fabsf(vv.x); sv.y += fabsf(vv.y);
            sv.z += fabsf(vv.z); sv.w += fabsf(vv.w);
        }
        float sa = (sv.x + sv.y) + (sv.z + sv.w);
        float so = __shfl_xor(sa, 1);
        if (half == 0) S_s[row] = (sa + so) * 1.001f;
    }
    __syncthreads();

    // per-lane constant byte-offsets (in shorts) for B-granule loads, code half 0
    int koff[8];
#pragma unroll
    for (int ks = 0; ks < 8; ++ks)
        koff[ks] = ((((ks * 4 + quad) << 10) + col) << 3);

    // ================= barrier-free single-pass chunk loop =================
    float bd1[4], bd2[4], bd3[4];
    int   cp_[4];
#pragma unroll
    for (int r = 0; r < 4; ++r) {
        bd1[r] = INFINITY; bd2[r] = INFINITY; bd3[r] = INFINITY; cp_[r] = 0;
    }

    for (int c = 0; c < CHUNKS; ++c) {
        const unsigned short* cb = embT + (c << 8);      // + c*32 codes (uniform)
        {
            u16x8 bfr[8];
#pragma unroll
            for (int ks = 0; ks < 8; ++ks)
                bfr[ks] = *(const u16x8*)(cb + koff[ks]);
            f32x4 acc = {0.f, 0.f, 0.f, 0.f};
#pragma unroll
            for (int ks = 0; ks < 8; ++ks)
                acc = __builtin_amdgcn_mfma_f32_16x16x32_bf16(afr[ks], *(bf16x8*)&bfr[ks], acc, 0, 0, 0);
            const int codeN = (c << 5) + col;
            const float eqv = esq_s[codeN];
#pragma unroll
            for (int r = 0; r < 4; ++r) {
                float s = __fmaf_rn(-2.0f, acc[r], eqv);
                INS(s, codeN, r);
            }
        }
        {
            u16x8 bfr[8];
#pragma unroll
            for (int ks = 0; ks < 8; ++ks)
                bfr[ks] = *(const u16x8*)(cb + koff[ks] + 128);
            f32x4 acc = {0.f, 0.f, 0.f, 0.f};
#pragma unroll
            for (int ks = 0; ks < 8; ++ks)
                acc = __builtin_amdgcn_mfma_f32_16x16x32_bf16(afr[ks], *(bf16x8*)&bfr[ks], acc, 0, 0, 0);
            const int codeN = (c << 5) + 16 + col;
            const float eqv = esq_s[codeN];
#pragma unroll
            for (int r = 0; r < 4; ++r) {
                float s = __fmaf_rn(-2.0f, acc[r], eqv);
                INS(s, codeN, r);
            }
        }
    }

    // ---- butterfly allreduce of bd1 across 16 code-columns (lex min) ----
    float th[4];
#pragma unroll
    for (int r = 0; r < 4; ++r) {
        unsigned long long kk =
            ((unsigned long long)encf(bd1[r]) << 32) | (unsigned)(cp_[r] & 0xFFFF);
#pragma unroll
        for (int msk = 1; msk <= 8; msk <<= 1) {
            unsigned long long o = __shfl_xor(kk, msk);
            if (o < kk) kk = o;
        }
        int row = row0 + quad * 4 + r;
        th[r] = decf((unsigned)(kk >> 32)) + (S_s[row] * (1.0f / 131072.0f) + 1e-4f);
    }

    // ---- candidate push + overflow flag (top-3 soundness) ----
#pragma unroll
    for (int r = 0; r < 4; ++r) {
        int row = row0 + quad * 4 + r;
        if (__builtin_expect(bd1[r] <= th[r], 0)) {
            unsigned i = atomicAdd(&cnt[row], 1u);
            if (i < CAP) list[row][i] = (unsigned short)(cp_[r] & 0xFFFF);
        }
        if (__builtin_expect(bd2[r] <= th[r], 0)) {
            unsigned i = atomicAdd(&cnt[row], 1u);
            if (i < CAP) list[row][i] = (unsigned short)((unsigned)cp_[r] >> 16);
        }
        if (__builtin_expect(bd3[r] <= th[r], 0))
            atomicAdd(&cnt[row], 1000u);     // may have dropped a candidate
    }
    __syncthreads();

    // ---- write per-row scratch record into out z_q region (overwritten later) ----
    if (tid < BMR) {
        unsigned* rec = (unsigned*)out + ((size_t)blk * BMR + tid) * SCR_WORDS;
        rec[0] = cnt[tid];
#pragma unroll
        for (int k = 0; k < 8; ++k)
            rec[1 + k] = (unsigned)list[tid][2 * k] | ((unsigned)list[tid][2 * k + 1] << 16);
    }
}

// ============ S2: exact rescore + fallback + index/histogram ================
__global__ void vq_rescore(
    const float* __restrict__ z, const float* __restrict__ emb,
    const float* __restrict__ esqg, float* __restrict__ out,
    unsigned int* __restrict__ count)
{
    __shared__ float esq_s[N_E];
    __shared__ float zsq_s[BMR];
    __shared__ int rowbest[BMR];
    __shared__ unsigned long long fb4[4];

    const int tid  = threadIdx.x;
    const int blk  = blockIdx.x;
    const int lane = tid & 63;
    const int w    = tid >> 6;
    const float* zb = z + (size_t)blk * BMR * EDIM;

    for (int i = tid; i < N_E; i += 256) esq_s[i] = esqg[i];
    __syncthreads();

    // ---- per-row zsq (numpy-pairwise exact) + candidate rescore, 4 lanes/row ----
    {
        int row = tid >> 2, j = tid & 3;
        const float* zrow = zb + row * EDIM;
        float h = (j < 2) ? pw128_sq(zrow + 128 * j) : 0.f;
        int base = lane & ~3;
        float v0 = __shfl(h, base);
        float v1 = __shfl(h, base + 1);
        float zq = __fadd_rn(v0, v1);
        if (j == 0) zsq_s[row] = zq;

        const unsigned* rec = (const unsigned*)out + ((size_t)blk * BMR + row) * SCR_WORDS;
        int cn = (int)rec[0];
        unsigned long long bkey = ~0ull;
        if (cn <= CAP) {
            for (int i = j; i < cn; i += 4) {
                unsigned pr = rec[1 + (i >> 1)];
                int n = (int)((i & 1) ? (pr >> 16) : (pr & 0xFFFF));
                float d = exact_d(zrow, emb + (size_t)n * EDIM, zq, esq_s[n]);
                unsigned long long k2 = ((unsigned long long)encf(d) << 32) | (unsigned)n;
                if (k2 < bkey) bkey = k2;
            }
        }
#pragma unroll
        for (int m = 1; m <= 2; m <<= 1) {
            unsigned long long o = __shfl_xor(bkey, m);
            if (o < bkey) bkey = o;
        }
        if (j == 0) rowbest[row] = (cn <= CAP) ? (int)(bkey & 0xFFFFFFFFu) : -1;
    }
    __syncthreads();

    // ---- overflow rows: full exact scan, block-cooperative (rare) ----
    for (int r = 0; r < BMR; ++r) {
        if (rowbest[r] != -1) continue;       // uniform branch
        const float* zr = zb + r * EDIM;
        float zqr = zsq_s[r];
        unsigned long long k = ~0ull;
        for (int ci = 0; ci < 4; ++ci) {
            int n = tid + ci * 256;
            float d = exact_d(zr, emb + (size_t)n * EDIM, zqr, esq_s[n]);
            unsigned long long k2 = ((unsigned long long)encf(d) << 32) | (unsigned)n;
            if (k2 < k) k = k2;
        }
#pragma unroll
        for (int msk = 1; msk <= 32; msk <<= 1) {
            unsigned long long o = __shfl_xor(k, msk);
            if (o < k) k = o;
        }
        if (lane == 0) fb4[w] = k;
        __syncthreads();
        if (tid == 0) {
            unsigned long long m0 = fb4[0] < fb4[1] ? fb4[0] : fb4[1];
            unsigned long long m1 = fb4[2] < fb4[3] ? fb4[2] : fb4[3];
            rowbest[r] = (int)((m0 < m1 ? m0 : m1) & 0xFFFFFFFFu);
        }
        __syncthreads();
    }

    // ---- write indices + histogram ----
    if (tid < BMR) {
        int bn = rowbest[tid];
        out[OUT2 + (size_t)blk * BMR + tid] = (float)bn;
        atomicAdd(&count[bn], 1u);
    }
}

// pure streaming: gather z_q = emb[idx], STE output, loss partial
__global__ void vq_output(const float* __restrict__ z, const float* __restrict__ emb,
                          float* __restrict__ out, double* __restrict__ lossSum)
{
    __shared__ double red4s[4];
    const int tid = threadIdx.x;
    const int blk = blockIdx.x;
    const int lane = tid & 63;
    const int w   = tid >> 6;
    const int row = tid >> 3;      // 0..31
    const int q   = tid & 7;       // 8 threads per row
    const size_t grow = (size_t)blk * OROWS + row;
    const int bn = (int)out[OUT2 + grow];
    const float4* zp4 = (const float4*)(z + grow * EDIM);
    const float4* ebr = (const float4*)(emb + (size_t)bn * EDIM);
    float4* outr = (float4*)(out + grow * EDIM);
    double lacc = 0.0;
#pragma unroll
    for (int i = 0; i < 8; ++i) {
        int k4 = q + i * 8;
        float4 zv = zp4[k4];
        float4 ev = ebr[k4];
        float4 o; float sd;
        sd = __fsub_rn(ev.x, zv.x); o.x = __fadd_rn(zv.x, sd); lacc += (double)__fmul_rn(sd, sd);
        sd = __fsub_rn(ev.y, zv.y); o.y = __fadd_rn(zv.y, sd); lacc += (double)__fmul_rn(sd, sd);
        sd = __fsub_rn(ev.z, zv.z); o.z = __fadd_rn(zv.z, sd); lacc += (double)__fmul_rn(sd, sd);
        sd = __fsub_rn(ev.w, zv.w); o.w = __fadd_rn(zv.w, sd); lacc += (double)__fmul_rn(sd, sd);
        outr[k4] = o;
    }
#pragma unroll
    for (int msk = 1; msk <= 32; msk <<= 1) lacc += __shfl_xor(lacc, msk);
    if (lane == 0) red4s[w] = lacc;
    __syncthreads();
    if (tid == 0) atomicAdd(lossSum, red4s[0] + red4s[1] + red4s[2] + red4s[3]);
}

__global__ void vq_finalize(const unsigned int* __restrict__ count,
                            const double* __restrict__ lossSum,
                            float* __restrict__ out)
{
    __shared__ double red[1024];
    int t = threadIdx.x;
    double em = (double)count[t] * (1.0 / 131072.0);
    red[t] = em * log(em + 1e-10);
    __syncthreads();
    for (int s = 512; s > 0; s >>= 1) {
        if (t < s) red[t] += red[t + s];
        __syncthreads();
    }
    if (t == 0) {
        out[OUT3] = (float)exp(-red[0]);
        double m = lossSum[0] * (1.0 / 33554432.0);
        out[OUT1] = (float)(1.25 * m);
    }
}

extern "C" void kernel_launch(void* const* d_in, const int* in_sizes, int n_in,
                              void* d_out, int out_size, void* d_ws, size_t ws_size,
                              hipStream_t stream) {
    const float* z   = (const float*)d_in[0];
    const float* emb = (const float*)d_in[1];
    float* out = (float*)d_out;

    unsigned short* embT = (unsigned short*)((char*)d_ws + WS_EMBT);
    float* esqg          = (float*)((char*)d_ws + WS_ESQ);
    unsigned int* count  = (unsigned int*)((char*)d_ws + WS_COUNT);
    double* lossSum      = (double*)((char*)d_ws + WS_LOSS);

    hipMemsetAsync((char*)d_ws + WS_COUNT, 0, 4104, stream);
    prep_emb<<<N_E, 64, 0, stream>>>(emb, embT, esqg);
    vq_scan<<<B_ROWS / BMR, 256, 0, stream>>>(z, embT, esqg, out);
    vq_rescore<<<B_ROWS / BMR, 256, 0, stream>>>(z, emb, esqg, out, count);
    vq_output<<<B_ROWS / OROWS, 256, 0, stream>>>(z, emb, out, lossSum);
    vq_finalize<<<1, 1024, 0, stream>>>(count, lossSum, out);
}

// Round 14
// 367.691 us; speedup vs baseline: 1.0665x; 1.0636x over previous
//
#include <hip/hip_runtime.h>

typedef __attribute__((ext_vector_type(8))) __bf16 bf16x8;
typedef __attribute__((ext_vector_type(4))) float f32x4;
typedef __attribute__((ext_vector_type(8))) unsigned short u16x8;

#define B_ROWS 131072
#define EDIM   256
#define N_E    1024
#define BMR    64          // rows per scan block (32 per wave, 2 row-halves x 2 code-halves)
#define CHUNKS 32          // 32 chunks x 32 codes (16 per nt-half)
#define CAP    16
#define OROWS  32          // rows per output block

#define OUT1 ((size_t)B_ROWS * EDIM)       // loss scalar
#define OUT2 (OUT1 + 1)                    // indices [B]
#define OUT3 (OUT2 + B_ROWS)               // perplexity scalar

// ws layout
#define WS_EMBT  0          // emb16T: [32 granules][1024 codes][8 bf16] = 524288 B
#define WS_ESQ   524288     // 1024 float
#define WS_COUNT 528384     // 1024 uint
#define WS_LOSS  532480     // 1 double

__device__ __forceinline__ unsigned short f2bf(float f) {   // RN to bf16
    unsigned u = __float_as_uint(f);
    return (unsigned short)((u + 0x7FFFu + ((u >> 16) & 1u)) >> 16);
}
__device__ __forceinline__ unsigned encf(float f) {          // order-preserving
    unsigned u = __float_as_uint(f);
    return u ^ (unsigned)(((int)u >> 31) | 0x80000000);
}
__device__ __forceinline__ float decf(unsigned x) {
    return (x & 0x80000000u) ? __uint_as_float(x ^ 0x80000000u)
                             : __uint_as_float(~x);
}
__device__ __forceinline__ float med3f(float a, float b, float c) {
#if __has_builtin(__builtin_amdgcn_fmed3f)
    return __builtin_amdgcn_fmed3f(a, b, c);
#else
    return fmaxf(fminf(a, b), fminf(fmaxf(a, b), c));
#endif
}

// numpy pairwise sum-of-squares over 128 elems (exact tree, no contraction)
__device__ inline float pw128_sq(const float* p) {
    float4 v0 = *(const float4*)p, v1 = *(const float4*)(p + 4);
    float r[8];
    r[0] = __fmul_rn(v0.x, v0.x); r[1] = __fmul_rn(v0.y, v0.y);
    r[2] = __fmul_rn(v0.z, v0.z); r[3] = __fmul_rn(v0.w, v0.w);
    r[4] = __fmul_rn(v1.x, v1.x); r[5] = __fmul_rn(v1.y, v1.y);
    r[6] = __fmul_rn(v1.z, v1.z); r[7] = __fmul_rn(v1.w, v1.w);
    for (int i = 8; i < 128; i += 8) {
        v0 = *(const float4*)(p + i); v1 = *(const float4*)(p + i + 4);
        r[0] = __fadd_rn(r[0], __fmul_rn(v0.x, v0.x));
        r[1] = __fadd_rn(r[1], __fmul_rn(v0.y, v0.y));
        r[2] = __fadd_rn(r[2], __fmul_rn(v0.z, v0.z));
        r[3] = __fadd_rn(r[3], __fmul_rn(v0.w, v0.w));
        r[4] = __fadd_rn(r[4], __fmul_rn(v1.x, v1.x));
        r[5] = __fadd_rn(r[5], __fmul_rn(v1.y, v1.y));
        r[6] = __fadd_rn(r[6], __fmul_rn(v1.z, v1.z));
        r[7] = __fadd_rn(r[7], __fmul_rn(v1.w, v1.w));
    }
    float s01 = __fadd_rn(r[0], r[1]), s23 = __fadd_rn(r[2], r[3]);
    float s45 = __fadd_rn(r[4], r[5]), s67 = __fadd_rn(r[6], r[7]);
    return __fadd_rn(__fadd_rn(s01, s23), __fadd_rn(s45, s67));
}

// exact fp32 distance, bit-identical to the verified rounds-1..13 chain
__device__ inline float exact_d(const float* zp, const float* ep, float zsq, float eq) {
    const float4* z4 = (const float4*)zp;
    const float4* e4 = (const float4*)ep;
    float acc = 0.f;
#pragma unroll 8
    for (int k = 0; k < 64; ++k) {
        float4 a = z4[k], b = e4[k];
        acc = __fmaf_rn(a.x, b.x, acc);
        acc = __fmaf_rn(a.y, b.y, acc);
        acc = __fmaf_rn(a.z, b.z, acc);
        acc = __fmaf_rn(a.w, b.w, acc);
    }
    return __fsub_rn(__fadd_rn(zsq, eq), 2.0f * acc);
}

// emb fp32 -> bf16, TRANSPOSED layout: embT[g][n] = 16B granule g of code n
__global__ void prep_emb(const float* __restrict__ emb,
                         unsigned short* __restrict__ embT,
                         float* __restrict__ esqg)
{
    int n = blockIdx.x, t = threadIdx.x;          // 1024 blocks x 64 threads
    const float4 v = ((const float4*)(emb + (size_t)n * EDIM))[t];
    ushort4 o = { f2bf(v.x), f2bf(v.y), f2bf(v.z), f2bf(v.w) };
    int g = t >> 1, j0 = (t & 1) * 4;
    *(ushort4*)(embT + ((size_t)g * N_E + n) * 8 + j0) = o;
    if (t < 2) {
        float h = pw128_sq(emb + (size_t)n * EDIM + 128 * t);
        float ho = __shfl_xor(h, 1);
        if (t == 0) esqg[n] = __fadd_rn(h, ho);
    }
}

// top-3 sorted insert (codes arrive in ascending order; strict < = first-index ties)
#define INS(s_, code_, r_)                                                  \
    {                                                                       \
        bool lt1 = (s_) < bd1[r_];                                          \
        bool lt2 = (s_) < bd2[r_];                                          \
        bd3[r_] = med3f((s_), bd2[r_], bd3[r_]);                            \
        bd2[r_] = med3f((s_), bd1[r_], bd2[r_]);                            \
        bd1[r_] = fminf((s_), bd1[r_]);                                     \
        int low_ = cp_[r_] & 0xFFFF;                                        \
        cp_[r_] = lt1 ? ((code_) | (low_ << 16))                            \
                      : (lt2 ? (low_ | ((code_) << 16)) : cp_[r_]);         \
    }

// ===== fused scan: MFMA top-3 + threshold + fast-path finalize ==============
__global__ __launch_bounds__(256, 2) void vq_scan(
    const float* __restrict__ z, const float* __restrict__ emb,
    const unsigned short* __restrict__ embT, const float* __restrict__ esqg,
    float* __restrict__ out, unsigned int* __restrict__ count)
{
    __shared__ float esq_s[N_E];                     // 4 KB
    __shared__ float zsq_s[BMR], S_s[BMR], thr_s[BMR];
    __shared__ unsigned long long wd64[2][BMR];      // 1 KB
    __shared__ unsigned cnt[BMR];
    __shared__ unsigned short list[BMR][CAP];        // 2 KB
    __shared__ int rowbest[BMR];
    __shared__ unsigned long long fb4[4];

    const int tid  = threadIdx.x;
    const int blk  = blockIdx.x;
    const int lane = tid & 63;
    const int w    = tid >> 6;
    const int col  = lane & 15;
    const int quad = lane >> 4;
    const int nt   = w >> 1;       // code half within each 32-code chunk
    const int mh   = w & 1;        // row half (rows 32*mh..+32)

    const float* zb = z + (size_t)blk * BMR * EDIM;

    for (int i = tid; i < N_E; i += 256) esq_s[i] = esqg[i];
    if (tid < BMR) cnt[tid] = 0u;

    // ---- A fragments from global z: 32 rows/wave = 64 VGPR ----
    bf16x8 afr[2][8];
#pragma unroll
    for (int mti = 0; mti < 2; ++mti) {
        int row = 32 * mh + 16 * mti + col;
#pragma unroll
        for (int ks = 0; ks < 8; ++ks) {
            const float* p = zb + row * EDIM + ((ks * 4 + quad) << 3);
            float4 a0 = *(const float4*)p;
            float4 a1 = *(const float4*)(p + 4);
            u16x8 t = { f2bf(a0.x), f2bf(a0.y), f2bf(a0.z), f2bf(a0.w),
                        f2bf(a1.x), f2bf(a1.y), f2bf(a1.z), f2bf(a1.w) };
            afr[mti][ks] = *(bf16x8*)&t;
        }
    }

    // ---- exact zsq (np-pairwise) + S = sum|z| (bound only) ----
    if (tid < 128) {
        int row = tid >> 1, half = tid & 1;
        const float* p = zb + row * EDIM + half * 128;
        float h = pw128_sq(p);
        const float4* p4 = (const float4*)p;
        float4 sv = {0.f, 0.f, 0.f, 0.f};
#pragma unroll
        for (int jj = 0; jj < 32; ++jj) {
            float4 vv = p4[jj];
            sv.x += fabsf(vv.x); sv.y += fabsf(vv.y);
            sv.z += fabsf(vv.z); sv.w += fabsf(vv.w);
        }
        float sa = (sv.x + sv.y) + (sv.z + sv.w);
        float ho = __shfl_xor(h, 1);
        float so = __shfl_xor(sa, 1);
        if (half == 0) {
            zsq_s[row] = __fadd_rn(h, ho);
            S_s[row]   = (sa + so) * 1.001f;
        }
    }
    __syncthreads();

    // per-lane constant offsets (in shorts) for the 8 B-granule loads
    int koff[8];
#pragma unroll
    for (int ks = 0; ks < 8; ++ks)
        koff[ks] = ((((ks * 4 + quad) << 10) + nt * 16 + col) << 3);

    // ================= barrier-free chunk loop: 8 slots =====================
    float bd1[8], bd2[8], bd3[8];
    int   cp_[8];
#pragma unroll
    for (int r = 0; r < 8; ++r) {
        bd1[r] = INFINITY; bd2[r] = INFINITY; bd3[r] = INFINITY; cp_[r] = 0;
    }

    for (int c = 0; c < CHUNKS; ++c) {
        const unsigned short* cb = embT + (c << 8);      // + c*32 codes (uniform)
        u16x8 bfr[8];
#pragma unroll
        for (int ks = 0; ks < 8; ++ks)
            bfr[ks] = *(const u16x8*)(cb + koff[ks]);
        f32x4 acc0 = {0.f, 0.f, 0.f, 0.f}, acc1 = {0.f, 0.f, 0.f, 0.f};
#pragma unroll
        for (int ks = 0; ks < 8; ++ks) {
            bf16x8 b = *(bf16x8*)&bfr[ks];
            acc0 = __builtin_amdgcn_mfma_f32_16x16x32_bf16(afr[0][ks], b, acc0, 0, 0, 0);
            acc1 = __builtin_amdgcn_mfma_f32_16x16x32_bf16(afr[1][ks], b, acc1, 0, 0, 0);
        }
        const int codeN = (c << 5) + nt * 16 + col;
        const float eqv = esq_s[codeN];
#pragma unroll
        for (int r = 0; r < 4; ++r) {
            float s0 = __fmaf_rn(-2.0f, acc0[r], eqv);
            INS(s0, codeN, r);
            float s1 = __fmaf_rn(-2.0f, acc1[r], eqv);
            INS(s1, codeN, 4 + r);
        }
    }

    // ---- butterfly per slot (lex min over 16 code-cols), cross-wave combine ----
#pragma unroll
    for (int mti = 0; mti < 2; ++mti)
#pragma unroll
        for (int r = 0; r < 4; ++r) {
            int slot = mti * 4 + r;
            unsigned long long kk =
                ((unsigned long long)encf(bd1[slot]) << 32) | (unsigned)(cp_[slot] & 0xFFFF);
#pragma unroll
            for (int msk = 1; msk <= 8; msk <<= 1) {
                unsigned long long o = __shfl_xor(kk, msk);
                if (o < kk) kk = o;
            }
            if (col == 0) wd64[nt][32 * mh + 16 * mti + 4 * quad + r] = kk;
        }
    __syncthreads();
    if (tid < BMR) {
        unsigned long long a = wd64[0][tid], b = wd64[1][tid];
        unsigned long long mn = a < b ? a : b;
        thr_s[tid] = decf((unsigned)(mn >> 32)) + (S_s[tid] * (1.0f / 131072.0f) + 1e-4f);
    }
    __syncthreads();

    // ---- candidate push + overflow flag (top-3 soundness) ----
#pragma unroll
    for (int mti = 0; mti < 2; ++mti)
#pragma unroll
        for (int r = 0; r < 4; ++r) {
            int slot = mti * 4 + r;
            int row = 32 * mh + 16 * mti + 4 * quad + r;
            float th = thr_s[row];
            if (__builtin_expect(bd1[slot] <= th, 0)) {
                unsigned i = atomicAdd(&cnt[row], 1u);
                if (i < CAP) list[row][i] = (unsigned short)(cp_[slot] & 0xFFFF);
            }
            if (__builtin_expect(bd2[slot] <= th, 0)) {
                unsigned i = atomicAdd(&cnt[row], 1u);
                if (i < CAP) list[row][i] = (unsigned short)((unsigned)cp_[slot] >> 16);
            }
            if (__builtin_expect(bd3[slot] <= th, 0))
                atomicAdd(&cnt[row], 1000u);     // may have dropped a candidate
        }
    __syncthreads();

    // ---- finalize per row (4 lanes): cnt==1 fast path, else exact rescore ----
    {
        int row = tid >> 2, j = tid & 3;
        int cn = (int)cnt[row];
        if (cn > CAP) {
            if (j == 0) rowbest[row] = -1;      // block fallback
        } else if (cn == 1) {
            // sound: argmin is in the candidate set; singleton => done, no exact_d
            if (j == 0) {
                int bn = (int)list[row][0];
                out[OUT2 + (size_t)blk * BMR + row] = (float)bn;
                atomicAdd(&count[bn], 1u);
                rowbest[row] = -2;
            }
        } else {
            float zq = zsq_s[row];
            const float* zrow = zb + row * EDIM;
            unsigned long long bkey = ~0ull;
            for (int i = j; i < cn; i += 4) {
                int n = (int)list[row][i];
                float d = exact_d(zrow, emb + (size_t)n * EDIM, zq, esq_s[n]);
                unsigned long long k2 = ((unsigned long long)encf(d) << 32) | (unsigned)n;
                if (k2 < bkey) bkey = k2;
            }
#pragma unroll
            for (int m = 1; m <= 2; m <<= 1) {
                unsigned long long o = __shfl_xor(bkey, m);
                if (o < bkey) bkey = o;
            }
            if (j == 0) {
                int bn = (int)(bkey & 0xFFFFFFFFu);
                out[OUT2 + (size_t)blk * BMR + row] = (float)bn;
                atomicAdd(&count[bn], 1u);
                rowbest[row] = -2;
            }
        }
    }
    __syncthreads();

    // ---- overflow rows: full exact scan, block-cooperative (rare) ----
    for (int r = 0; r < BMR; ++r) {
        if (rowbest[r] != -1) continue;       // uniform branch
        const float* zr = zb + r * EDIM;
        float zqr = zsq_s[r];
        unsigned long long k = ~0ull;
        for (int ci = 0; ci < 4; ++ci) {
            int n = tid + ci * 256;
            float d = exact_d(zr, emb + (size_t)n * EDIM, zqr, esq_s[n]);
            unsigned long long k2 = ((unsigned long long)encf(d) << 32) | (unsigned)n;
            if (k2 < k) k = k2;
        }
#pragma unroll
        for (int msk = 1; msk <= 32; msk <<= 1) {
            unsigned long long o = __shfl_xor(k, msk);
            if (o < k) k = o;
        }
        if (lane == 0) fb4[w] = k;
        __syncthreads();
        if (tid == 0) {
            unsigned long long m0 = fb4[0] < fb4[1] ? fb4[0] : fb4[1];
            unsigned long long m1 = fb4[2] < fb4[3] ? fb4[2] : fb4[3];
            int bn = (int)((m0 < m1 ? m0 : m1) & 0xFFFFFFFFu);
            out[OUT2 + (size_t)blk * BMR + r] = (float)bn;
            atomicAdd(&count[bn], 1u);
        }
        __syncthreads();
    }
}

// pure streaming: gather z_q = emb[idx], STE output, loss partial
__global__ void vq_output(const float* __restrict__ z, const float* __restrict__ emb,
                          float* __restrict__ out, double* __restrict__ lossSum)
{
    __shared__ double red4s[4];
    const int tid = threadIdx.x;
    const int blk = blockIdx.x;
    const int lane = tid & 63;
    const int w   = tid >> 6;
    const int row = tid >> 3;      // 0..31
    const int q   = tid & 7;       // 8 threads per row
    const size_t grow = (size_t)blk * OROWS + row;
    const int bn = (int)out[OUT2 + grow];
    const float4* zp4 = (const float4*)(z + grow * EDIM);
    const float4* ebr = (const float4*)(emb + (size_t)bn * EDIM);
    float4* outr = (float4*)(out + grow * EDIM);
    double lacc = 0.0;
#pragma unroll
    for (int i = 0; i < 8; ++i) {
        int k4 = q + i * 8;
        float4 zv = zp4[k4];
        float4 ev = ebr[k4];
        float4 o; float sd;
        sd = __fsub_rn(ev.x, zv.x); o.x = __fadd_rn(zv.x, sd); lacc += (double)__fmul_rn(sd, sd);
        sd = __fsub_rn(ev.y, zv.y); o.y = __fadd_rn(zv.y, sd); lacc += (double)__fmul_rn(sd, sd);
        sd = __fsub_rn(ev.z, zv.z); o.z = __fadd_rn(zv.z, sd); lacc += (double)__fmul_rn(sd, sd);
        sd = __fsub_rn(ev.w, zv.w); o.w = __fadd_rn(zv.w, sd); lacc += (double)__fmul_rn(sd, sd);
        outr[k4] = o;
    }
#pragma unroll
    for (int msk = 1; msk <= 32; msk <<= 1) lacc += __shfl_xor(lacc, msk);
    if (lane == 0) red4s[w] = lacc;
    __syncthreads();
    if (tid == 0) atomicAdd(lossSum, red4s[0] + red4s[1] + red4s[2] + red4s[3]);
}

__global__ void vq_finalize(const unsigned int* __restrict__ count,
                            const double* __restrict__ lossSum,
                            float* __restrict__ out)
{
    __shared__ double red[1024];
    int t = threadIdx.x;
    double em = (double)count[t] * (1.0 / 131072.0);
    red[t] = em * log(em + 1e-10);
    __syncthreads();
    for (int s = 512; s > 0; s >>= 1) {
        if (t < s) red[t] += red[t + s];
        __syncthreads();
    }
    if (t == 0) {
        out[OUT3] = (float)exp(-red[0]);
        double m = lossSum[0] * (1.0 / 33554432.0);
        out[OUT1] = (float)(1.25 * m);
    }
}

extern "C" void kernel_launch(void* const* d_in, const int* in_sizes, int n_in,
                              void* d_out, int out_size, void* d_ws, size_t ws_size,
                              hipStream_t stream) {
    const float* z   = (const float*)d_in[0];
    const float* emb = (const float*)d_in[1];
    float* out = (float*)d_out;

    unsigned short* embT = (unsigned short*)((char*)d_ws + WS_EMBT);
    float* esqg          = (float*)((char*)d_ws + WS_ESQ);
    unsigned int* count  = (unsigned int*)((char*)d_ws + WS_COUNT);
    double* lossSum      = (double*)((char*)d_ws + WS_LOSS);

    hipMemsetAsync((char*)d_ws + WS_COUNT, 0, 4104, stream);
    prep_emb<<<N_E, 64, 0, stream>>>(emb, embT, esqg);
    vq_scan<<<B_ROWS / BMR, 256, 0, stream>>>(z, emb, embT, esqg, out, count);
    vq_output<<<B_ROWS / OROWS, 256, 0, stream>>>(z, emb, out, lossSum);
    vq_finalize<<<1, 1024, 0, stream>>>(count, lossSum, out);
}

// Round 15
// 365.317 us; speedup vs baseline: 1.0735x; 1.0065x over previous
//
#include <hip/hip_runtime.h>

typedef __attribute__((ext_vector_type(8))) __bf16 bf16x8;
typedef __attribute__((ext_vector_type(4))) float f32x4;
typedef __attribute__((ext_vector_type(8))) unsigned short u16x8;

#define B_ROWS 131072
#define EDIM   256
#define N_E    1024
#define BMR    64          // rows per scan block (16 per wave)
#define CHUNKS 32          // 32 chunks x 32 codes (2 halves of 16)
#define CAP    16
#define OROWS  32          // rows per output block

#define OUT1 ((size_t)B_ROWS * EDIM)       // loss scalar
#define OUT2 (OUT1 + 1)                    // indices [B]
#define OUT3 (OUT2 + B_ROWS)               // perplexity scalar
#define SCR_WORDS 10                       // per-row scratch record (u32s) in out[0..]

// ws layout
#define WS_EMBT  0          // emb16T: [32 granules][1024 codes][8 bf16] = 524288 B
#define WS_ESQ   524288     // 1024 float
#define WS_COUNT 528384     // 1024 uint
#define WS_LOSS  532480     // 1 double

__device__ __forceinline__ unsigned short f2bf(float f) {   // RN to bf16
    unsigned u = __float_as_uint(f);
    return (unsigned short)((u + 0x7FFFu + ((u >> 16) & 1u)) >> 16);
}
__device__ __forceinline__ unsigned encf(float f) {          // order-preserving
    unsigned u = __float_as_uint(f);
    return u ^ (unsigned)(((int)u >> 31) | 0x80000000);
}
__device__ __forceinline__ float decf(unsigned x) {
    return (x & 0x80000000u) ? __uint_as_float(x ^ 0x80000000u)
                             : __uint_as_float(~x);
}
__device__ __forceinline__ float med3f(float a, float b, float c) {
#if __has_builtin(__builtin_amdgcn_fmed3f)
    return __builtin_amdgcn_fmed3f(a, b, c);
#else
    return fmaxf(fminf(a, b), fminf(fmaxf(a, b), c));
#endif
}

// numpy pairwise sum-of-squares over 128 elems (exact tree, no contraction)
__device__ inline float pw128_sq(const float* p) {
    float4 v0 = *(const float4*)p, v1 = *(const float4*)(p + 4);
    float r[8];
    r[0] = __fmul_rn(v0.x, v0.x); r[1] = __fmul_rn(v0.y, v0.y);
    r[2] = __fmul_rn(v0.z, v0.z); r[3] = __fmul_rn(v0.w, v0.w);
    r[4] = __fmul_rn(v1.x, v1.x); r[5] = __fmul_rn(v1.y, v1.y);
    r[6] = __fmul_rn(v1.z, v1.z); r[7] = __fmul_rn(v1.w, v1.w);
    for (int i = 8; i < 128; i += 8) {
        v0 = *(const float4*)(p + i); v1 = *(const float4*)(p + i + 4);
        r[0] = __fadd_rn(r[0], __fmul_rn(v0.x, v0.x));
        r[1] = __fadd_rn(r[1], __fmul_rn(v0.y, v0.y));
        r[2] = __fadd_rn(r[2], __fmul_rn(v0.z, v0.z));
        r[3] = __fadd_rn(r[3], __fmul_rn(v0.w, v0.w));
        r[4] = __fadd_rn(r[4], __fmul_rn(v1.x, v1.x));
        r[5] = __fadd_rn(r[5], __fmul_rn(v1.y, v1.y));
        r[6] = __fadd_rn(r[6], __fmul_rn(v1.z, v1.z));
        r[7] = __fadd_rn(r[7], __fmul_rn(v1.w, v1.w));
    }
    float s01 = __fadd_rn(r[0], r[1]), s23 = __fadd_rn(r[2], r[3]);
    float s45 = __fadd_rn(r[4], r[5]), s67 = __fadd_rn(r[6], r[7]);
    return __fadd_rn(__fadd_rn(s01, s23), __fadd_rn(s45, s67));
}

// exact fp32 distance, bit-identical to the verified rounds-1..14 chain
__device__ inline float exact_d(const float* zp, const float* ep, float zsq, float eq) {
    const float4* z4 = (const float4*)zp;
    const float4* e4 = (const float4*)ep;
    float acc = 0.f;
#pragma unroll 8
    for (int k = 0; k < 64; ++k) {
        float4 a = z4[k], b = e4[k];
        acc = __fmaf_rn(a.x, b.x, acc);
        acc = __fmaf_rn(a.y, b.y, acc);
        acc = __fmaf_rn(a.z, b.z, acc);
        acc = __fmaf_rn(a.w, b.w, acc);
    }
    return __fsub_rn(__fadd_rn(zsq, eq), 2.0f * acc);
}

// emb fp32 -> bf16, TRANSPOSED layout: embT[g][n] = 16B granule g of code n
__global__ void prep_emb(const float* __restrict__ emb,
                         unsigned short* __restrict__ embT,
                         float* __restrict__ esqg)
{
    int n = blockIdx.x, t = threadIdx.x;          // 1024 blocks x 64 threads
    const float4 v = ((const float4*)(emb + (size_t)n * EDIM))[t];
    ushort4 o = { f2bf(v.x), f2bf(v.y), f2bf(v.z), f2bf(v.w) };
    int g = t >> 1, j0 = (t & 1) * 4;
    *(ushort4*)(embT + ((size_t)g * N_E + n) * 8 + j0) = o;
    if (t < 2) {
        float h = pw128_sq(emb + (size_t)n * EDIM + 128 * t);
        float ho = __shfl_xor(h, 1);
        if (t == 0) esqg[n] = __fadd_rn(h, ho);
    }
}

// top-3 sorted insert (value set is visit-order-invariant; ties force cnt>=2
// or bd3<=th overflow, both handled exactly downstream)
#define INS(s_, code_, r_)                                                  \
    {                                                                       \
        bool lt1 = (s_) < bd1[r_];                                          \
        bool lt2 = (s_) < bd2[r_];                                          \
        bd3[r_] = med3f((s_), bd2[r_], bd3[r_]);                            \
        bd2[r_] = med3f((s_), bd1[r_], bd2[r_]);                            \
        bd1[r_] = fminf((s_), bd1[r_]);                                     \
        int low_ = cp_[r_] & 0xFFFF;                                        \
        cp_[r_] = lt1 ? ((code_) | (low_ << 16))                            \
                      : (lt2 ? (low_ | ((code_) << 16)) : cp_[r_]);         \
    }

// ============ S1: MFMA scan + threshold + cnt==1 fast-path ==================
__global__ __launch_bounds__(256, 4) void vq_scan(
    const float* __restrict__ z, const unsigned short* __restrict__ embT,
    const float* __restrict__ esqg, float* __restrict__ out,
    unsigned int* __restrict__ count)
{
    __shared__ float esq_s[N_E];                     // 4 KB
    __shared__ float S_s[BMR];
    __shared__ unsigned cnt[BMR];
    __shared__ unsigned short list[BMR][CAP];        // 2 KB

    const int tid  = threadIdx.x;
    const int blk  = blockIdx.x;
    const int lane = tid & 63;
    const int w    = tid >> 6;
    const int col  = lane & 15;
    const int quad = lane >> 4;
    const int row0 = w * 16;       // this wave owns rows row0..row0+15, ALL codes
    const int coff = ((blk << 2) | w) & 31;   // per-wave chunk stagger (L2 spread)

    const float* zb = z + (size_t)blk * BMR * EDIM;

    for (int i = tid; i < N_E; i += 256) esq_s[i] = esqg[i];
    if (tid < BMR) cnt[tid] = 0u;

    // ---- A fragments from global z (one-time): 16 rows/wave = 32 VGPR ----
    bf16x8 afr[8];
    {
        int row = row0 + col;
#pragma unroll
        for (int ks = 0; ks < 8; ++ks) {
            const float* p = zb + row * EDIM + ((ks * 4 + quad) << 3);
            float4 a0 = *(const float4*)p;
            float4 a1 = *(const float4*)(p + 4);
            u16x8 t = { f2bf(a0.x), f2bf(a0.y), f2bf(a0.z), f2bf(a0.w),
                        f2bf(a1.x), f2bf(a1.y), f2bf(a1.z), f2bf(a1.w) };
            afr[ks] = *(bf16x8*)&t;
        }
    }

    // ---- S = sum|z| per row (margin bound only) ----
    if (tid < 128) {
        int row = tid >> 1, half = tid & 1;
        const float4* p4 = (const float4*)(zb + row * EDIM + half * 128);
        float4 sv = {0.f, 0.f, 0.f, 0.f};
#pragma unroll
        for (int jj = 0; jj < 32; ++jj) {
            float4 vv = p4[jj];
            sv.x += fabsf(vv.x); sv.y += fabsf(vv.y);
            sv.z += fabsf(vv.z); sv.w += fabsf(vv.w);
        }
        float sa = (sv.x + sv.y) + (sv.z + sv.w);
        float so = __shfl_xor(sa, 1);
        if (half == 0) S_s[row] = (sa + so) * 1.001f;
    }
    __syncthreads();

    // per-lane constant byte-offsets (in shorts) for B-granule loads, code half 0
    int koff[8];
#pragma unroll
    for (int ks = 0; ks < 8; ++ks)
        koff[ks] = ((((ks * 4 + quad) << 10) + col) << 3);

    // ================= barrier-free chunk loop (staggered order) ===========
    float bd1[4], bd2[4], bd3[4];
    int   cp_[4];
#pragma unroll
    for (int r = 0; r < 4; ++r) {
        bd1[r] = INFINITY; bd2[r] = INFINITY; bd3[r] = INFINITY; cp_[r] = 0;
    }

    for (int c = 0; c < CHUNKS; ++c) {
        const int cc = (c + coff) & 31;
        const unsigned short* cb = embT + (cc << 8);     // + cc*32 codes (uniform)
        {
            u16x8 bfr[8];
#pragma unroll
            for (int ks = 0; ks < 8; ++ks)
                bfr[ks] = *(const u16x8*)(cb + koff[ks]);
            f32x4 acc = {0.f, 0.f, 0.f, 0.f};
#pragma unroll
            for (int ks = 0; ks < 8; ++ks)
                acc = __builtin_amdgcn_mfma_f32_16x16x32_bf16(afr[ks], *(bf16x8*)&bfr[ks], acc, 0, 0, 0);
            const int codeN = (cc << 5) + col;
            const float eqv = esq_s[codeN];
#pragma unroll
            for (int r = 0; r < 4; ++r) {
                float s = __fmaf_rn(-2.0f, acc[r], eqv);
                INS(s, codeN, r);
            }
        }
        {
            u16x8 bfr[8];
#pragma unroll
            for (int ks = 0; ks < 8; ++ks)
                bfr[ks] = *(const u16x8*)(cb + koff[ks] + 128);
            f32x4 acc = {0.f, 0.f, 0.f, 0.f};
#pragma unroll
            for (int ks = 0; ks < 8; ++ks)
                acc = __builtin_amdgcn_mfma_f32_16x16x32_bf16(afr[ks], *(bf16x8*)&bfr[ks], acc, 0, 0, 0);
            const int codeN = (cc << 5) + 16 + col;
            const float eqv = esq_s[codeN];
#pragma unroll
            for (int r = 0; r < 4; ++r) {
                float s = __fmaf_rn(-2.0f, acc[r], eqv);
                INS(s, codeN, r);
            }
        }
    }

    // ---- butterfly allreduce of bd1 across 16 code-columns (lex min) ----
    float th[4];
#pragma unroll
    for (int r = 0; r < 4; ++r) {
        unsigned long long kk =
            ((unsigned long long)encf(bd1[r]) << 32) | (unsigned)(cp_[r] & 0xFFFF);
#pragma unroll
        for (int msk = 1; msk <= 8; msk <<= 1) {
            unsigned long long o = __shfl_xor(kk, msk);
            if (o < kk) kk = o;
        }
        int row = row0 + quad * 4 + r;
        th[r] = decf((unsigned)(kk >> 32)) + (S_s[row] * (1.0f / 131072.0f) + 1e-4f);
    }

    // ---- candidate push + overflow flag (top-3 soundness) ----
#pragma unroll
    for (int r = 0; r < 4; ++r) {
        int row = row0 + quad * 4 + r;
        if (__builtin_expect(bd1[r] <= th[r], 0)) {
            unsigned i = atomicAdd(&cnt[row], 1u);
            if (i < CAP) list[row][i] = (unsigned short)(cp_[r] & 0xFFFF);
        }
        if (__builtin_expect(bd2[r] <= th[r], 0)) {
            unsigned i = atomicAdd(&cnt[row], 1u);
            if (i < CAP) list[row][i] = (unsigned short)((unsigned)cp_[r] >> 16);
        }
        if (__builtin_expect(bd3[r] <= th[r], 0))
            atomicAdd(&cnt[row], 1000u);     // may have dropped a candidate
    }
    __syncthreads();

    // ---- epilogue: cnt==1 fast path (sound: singleton candidate set) ------
    if (tid < BMR) {
        int row = tid;
        unsigned cn = cnt[row];
        unsigned* rec = (unsigned*)out + ((size_t)blk * BMR + row) * SCR_WORDS;
        rec[0] = cn;
        if (cn == 1u) {
            int bn = (int)list[row][0];
            out[OUT2 + (size_t)blk * BMR + row] = (float)bn;
            atomicAdd(&count[bn], 1u);
        } else if (cn <= CAP) {
#pragma unroll
            for (int k = 0; k < 8; ++k)
                rec[1 + k] = (unsigned)list[row][2 * k]
                           | ((unsigned)list[row][2 * k + 1] << 16);
        }
    }
}

// ============ S2: lean rescore (only cnt>=2 rows touch z) ===================
__global__ void vq_rescore(
    const float* __restrict__ z, const float* __restrict__ emb,
    const float* __restrict__ esqg, float* __restrict__ out,
    unsigned int* __restrict__ count)
{
    __shared__ float esq_s[N_E];
    __shared__ int rowbest[BMR];     // -2 done/skip, -1 overflow
    __shared__ float zq_fb;
    __shared__ unsigned long long fb4[4];

    const int tid  = threadIdx.x;
    const int blk  = blockIdx.x;
    const int lane = tid & 63;
    const int w    = tid >> 6;
    const float* zb = z + (size_t)blk * BMR * EDIM;

    for (int i = tid; i < N_E; i += 256) esq_s[i] = esqg[i];
    __syncthreads();

    {
        int row = tid >> 2, j = tid & 3;
        const unsigned* rec = (const unsigned*)out + ((size_t)blk * BMR + row) * SCR_WORDS;
        int cn = (int)rec[0];
        if (cn > CAP) {
            if (j == 0) rowbest[row] = -1;
        } else if (cn >= 2) {
            const float* zrow = zb + row * EDIM;
            float h = (j < 2) ? pw128_sq(zrow + 128 * j) : 0.f;
            int base = lane & ~3;
            float v0 = __shfl(h, base);
            float v1 = __shfl(h, base + 1);
            float zq = __fadd_rn(v0, v1);
            unsigned long long bkey = ~0ull;
            for (int i = j; i < cn; i += 4) {
                unsigned pr = rec[1 + (i >> 1)];
                int n = (int)((i & 1) ? (pr >> 16) : (pr & 0xFFFF));
                float d = exact_d(zrow, emb + (size_t)n * EDIM, zq, esq_s[n]);
                unsigned long long k2 = ((unsigned long long)encf(d) << 32) | (unsigned)n;
                if (k2 < bkey) bkey = k2;
            }
#pragma unroll
            for (int m = 1; m <= 2; m <<= 1) {
                unsigned long long o = __shfl_xor(bkey, m);
                if (o < bkey) bkey = o;
            }
            if (j == 0) {
                int bn = (int)(bkey & 0xFFFFFFFFu);
                out[OUT2 + (size_t)blk * BMR + row] = (float)bn;
                atomicAdd(&count[bn], 1u);
                rowbest[row] = -2;
            }
        } else {
            if (j == 0) rowbest[row] = -2;   // cnt==1 handled in scan
        }
    }
    __syncthreads();

    // ---- overflow rows: full exact scan, block-cooperative (rare) ----
    for (int r = 0; r < BMR; ++r) {
        if (rowbest[r] != -1) continue;       // uniform branch
        const float* zr = zb + r * EDIM;
        if (tid == 0)
            zq_fb = __fadd_rn(pw128_sq(zr), pw128_sq(zr + 128));
        __syncthreads();
        float zqr = zq_fb;
        unsigned long long k = ~0ull;
        for (int ci = 0; ci < 4; ++ci) {
            int n = tid + ci * 256;
            float d = exact_d(zr, emb + (size_t)n * EDIM, zqr, esq_s[n]);
            unsigned long long k2 = ((unsigned long long)encf(d) << 32) | (unsigned)n;
            if (k2 < k) k = k2;
        }
#pragma unroll
        for (int msk = 1; msk <= 32; msk <<= 1) {
            unsigned long long o = __shfl_xor(k, msk);
            if (o < k) k = o;
        }
        if (lane == 0) fb4[w] = k;
        __syncthreads();
        if (tid == 0) {
            unsigned long long m0 = fb4[0] < fb4[1] ? fb4[0] : fb4[1];
            unsigned long long m1 = fb4[2] < fb4[3] ? fb4[2] : fb4[3];
            int bn = (int)((m0 < m1 ? m0 : m1) & 0xFFFFFFFFu);
            out[OUT2 + (size_t)blk * BMR + r] = (float)bn;
            atomicAdd(&count[bn], 1u);
        }
        __syncthreads();
    }
}

// pure streaming: gather z_q = emb[idx], STE output, loss partial
__global__ void vq_output(const float* __restrict__ z, const float* __restrict__ emb,
                          float* __restrict__ out, double* __restrict__ lossSum)
{
    __shared__ double red4s[4];
    const int tid = threadIdx.x;
    const int blk = blockIdx.x;
    const int lane = tid & 63;
    const int w   = tid >> 6;
    const int row = tid >> 3;      // 0..31
    const int q   = tid & 7;       // 8 threads per row
    const size_t grow = (size_t)blk * OROWS + row;
    const int bn = (int)out[OUT2 + grow];
    const float4* zp4 = (const float4*)(z + grow * EDIM);
    const float4* ebr = (const float4*)(emb + (size_t)bn * EDIM);
    float4* outr = (float4*)(out + grow * EDIM);
    double lacc = 0.0;
#pragma unroll
    for (int i = 0; i < 8; ++i) {
        int k4 = q + i * 8;
        float4 zv = zp4[k4];
        float4 ev = ebr[k4];
        float4 o; float sd;
        sd = __fsub_rn(ev.x, zv.x); o.x = __fadd_rn(zv.x, sd); lacc += (double)__fmul_rn(sd, sd);
        sd = __fsub_rn(ev.y, zv.y); o.y = __fadd_rn(zv.y, sd); lacc += (double)__fmul_rn(sd, sd);
        sd = __fsub_rn(ev.z, zv.z); o.z = __fadd_rn(zv.z, sd); lacc += (double)__fmul_rn(sd, sd);
        sd = __fsub_rn(ev.w, zv.w); o.w = __fadd_rn(zv.w, sd); lacc += (double)__fmul_rn(sd, sd);
        outr[k4] = o;
    }
#pragma unroll
    for (int msk = 1; msk <= 32; msk <<= 1) lacc += __shfl_xor(lacc, msk);
    if (lane == 0) red4s[w] = lacc;
    __syncthreads();
    if (tid == 0) atomicAdd(lossSum, red4s[0] + red4s[1] + red4s[2] + red4s[3]);
}

__global__ void vq_finalize(const unsigned int* __restrict__ count,
                            const double* __restrict__ lossSum,
                            float* __restrict__ out)
{
    __shared__ double red[1024];
    int t = threadIdx.x;
    double em = (double)count[t] * (1.0 / 131072.0);
    red[t] = em * log(em + 1e-10);
    __syncthreads();
    for (int s = 512; s > 0; s >>= 1) {
        if (t < s) red[t] += red[t + s];
        __syncthreads();
    }
    if (t == 0) {
        out[OUT3] = (float)exp(-red[0]);
        double m = lossSum[0] * (1.0 / 33554432.0);
        out[OUT1] = (float)(1.25 * m);
    }
}

extern "C" void kernel_launch(void* const* d_in, const int* in_sizes, int n_in,
                              void* d_out, int out_size, void* d_ws, size_t ws_size,
                              hipStream_t stream) {
    const float* z   = (const float*)d_in[0];
    const float* emb = (const float*)d_in[1];
    float* out = (float*)d_out;

    unsigned short* embT = (unsigned short*)((char*)d_ws + WS_EMBT);
    float* esqg          = (float*)((char*)d_ws + WS_ESQ);
    unsigned int* count  = (unsigned int*)((char*)d_ws + WS_COUNT);
    double* lossSum      = (double*)((char*)d_ws + WS_LOSS);

    hipMemsetAsync((char*)d_ws + WS_COUNT, 0, 4104, stream);
    prep_emb<<<N_E, 64, 0, stream>>>(emb, embT, esqg);
    vq_scan<<<B_ROWS / BMR, 256, 0, stream>>>(z, embT, esqg, out, count);
    vq_rescore<<<B_ROWS / BMR, 256, 0, stream>>>(z, emb, esqg, out, count);
    vq_output<<<B_ROWS / OROWS, 256, 0, stream>>>(z, emb, out, lossSum);
    vq_finalize<<<1, 1024, 0, stream>>>(count, lossSum, out);
}